// Round 4
// baseline (1415.722 us; speedup 1.0000x reference)
//
#include <hip/hip_runtime.h>

// ---------------------------------------------------------------------------
// GraphTrajSimEncoder on MI355X — round 3 (resubmit; R3 bench was an infra
// GPUAcquisitionTimeout, no signal).
// R2 post-mortem: k_agg gather was L2-miss bound (FETCH 379MB/dispatch = full
// E x 512B, table >> 4MB per-XCD L2). Fix: feature-chunked aggregation with
// chunk-major node-feature layout [c][N][32] (3.2MB slice fits one XCD L2) and
// chunk->XCD pinning via blockIdx.x & 7. Weights K-permuted to match chunked
// A12; GEMM A-staging and epilogue handle chunk-major addressing.
// ---------------------------------------------------------------------------

using bf16x8  = __attribute__((ext_vector_type(8))) __bf16;
using floatx4 = __attribute__((ext_vector_type(4))) float;

__device__ __forceinline__ float b2f(unsigned short b) {
    return __uint_as_float(((unsigned)b) << 16);
}
__device__ __forceinline__ unsigned short f2b(float f) {
    unsigned u = __float_as_uint(f);
    return (unsigned short)((u + 0x7FFFu + ((u >> 16) & 1u)) >> 16);
}
__device__ __forceinline__ unsigned short f2h(float f) {
    _Float16 h = (_Float16)f;
    return __builtin_bit_cast(unsigned short, h);
}
__device__ __forceinline__ float h2f(unsigned short u) {
    return (float)__builtin_bit_cast(_Float16, u);
}

// ---------------- graph preprocessing ----------------

__global__ void k_cnt2(const int* __restrict__ col0, const int* __restrict__ col1,
                       int E, int* __restrict__ cnt0, int* __restrict__ cnt1) {
    int e = blockIdx.x * 256 + threadIdx.x;
    const int* col = blockIdx.y ? col1 : col0;
    int* cnt = blockIdx.y ? cnt1 : cnt0;
    if (e < E) atomicAdd(&cnt[col[e]], 1);
}

// grid (1,2): one block scans one set. off[0]=0, off[i+1]=sum(cnt[0..i])
__global__ __launch_bounds__(1024) void k_scan2(
    const int* __restrict__ cnt0, const int* __restrict__ cnt1,
    int* __restrict__ off0, int* __restrict__ off1, int n) {
    const int* cnt = blockIdx.y ? cnt1 : cnt0;
    int* off = blockIdx.y ? off1 : off0;
    __shared__ int wsum[16];
    __shared__ int wpre[16];
    __shared__ int carry;
    const int t = threadIdx.x;
    const int lane = t & 63;
    const int w = t >> 6;
    if (t == 0) { carry = 0; off[0] = 0; }
    __syncthreads();
    for (int base = 0; base < n; base += 1024) {
        int i = base + t;
        int v = (i < n) ? cnt[i] : 0;
        #pragma unroll
        for (int d = 1; d < 64; d <<= 1) {
            int u = __shfl_up(v, d, 64);
            if (lane >= d) v += u;
        }
        if (lane == 63) wsum[w] = v;
        __syncthreads();
        if (t < 16) {
            int s = wsum[t];
            #pragma unroll
            for (int d = 1; d < 16; d <<= 1) {
                int u = __shfl_up(s, d, 16);
                if (t >= d) s += u;
            }
            wpre[t] = s;
        }
        __syncthreads();
        int add = carry + (w > 0 ? wpre[w - 1] : 0);
        if (i < n) off[i + 1] = v + add;
        __syncthreads();
        if (t == 0) carry += wpre[15];
        __syncthreads();
    }
}

// dinv = rsqrt(deg+1) (self loop), cur = off  — grid (gN,2)
__global__ void k_prep(const int* __restrict__ cnt0, const int* __restrict__ cnt1,
                       const int* __restrict__ off0, const int* __restrict__ off1,
                       float* __restrict__ dinv0, float* __restrict__ dinv1,
                       int* __restrict__ cur0, int* __restrict__ cur1, int n) {
    int i = blockIdx.x * 256 + threadIdx.x;
    if (i >= n) return;
    const int* cnt = blockIdx.y ? cnt1 : cnt0;
    const int* off = blockIdx.y ? off1 : off0;
    float* dinv = blockIdx.y ? dinv1 : dinv0;
    int* cur = blockIdx.y ? cur1 : cur0;
    dinv[i] = rsqrtf((float)(cnt[i] + 1));
    cur[i] = off[i];
}

// CSR fill: single 4B record per edge = (src:u16 | fp16(w2) << 16).
__global__ void k_fill2(const int* __restrict__ ei0, const float* __restrict__ ea0,
                        const int* __restrict__ ei1, const float* __restrict__ ea1,
                        int E, int* __restrict__ cur0, int* __restrict__ cur1,
                        unsigned* __restrict__ rec0, unsigned* __restrict__ rec1) {
    int e = blockIdx.x * 256 + threadIdx.x;
    if (e >= E) return;
    const int* ei = blockIdx.y ? ei1 : ei0;
    const float* ea = blockIdx.y ? ea1 : ea0;
    int* cur = blockIdx.y ? cur1 : cur0;
    unsigned* rec = blockIdx.y ? rec1 : rec0;
    int r = ei[e];          // source (row)
    int c = ei[E + e];      // target (col)
    float a = ea[e];
    float w2 = (a > 0.0f) ? fminf(rsqrtf(a), 1.0f) : 0.0f;
    int p = atomicAdd(&cur[c], 1);
    rec[p] = (unsigned)r | ((unsigned)f2h(w2) << 16);   // requires N < 65536
}

// ---------------- dtype conversions ----------------

// xc[i][k] (bf16, K padded to KP): k<F -> x, k<KC -> d2an, else 0  (row-major)
__global__ void k_xc(const float* __restrict__ x, const float* __restrict__ pe,
                     unsigned short* __restrict__ xc, int n, int F, int PEd,
                     int KC, int KP) {
    int idx = blockIdx.x * 256 + threadIdx.x;
    if (idx >= n * KP) return;
    int i = idx / KP, k = idx - i * KP;
    float v = 0.0f;
    if (k < F)        v = x[(size_t)i * F + k];
    else if (k < KC)  v = pe[(size_t)i * PEd + (k - F)];
    xc[idx] = f2b(v);
}

// weight conversions:
//   seg 0/1: Wn [F][KC] f32 -> [F][KP] bf16 zero-padded (row-major K)
//   seg 2..5: [Wa|Wb] -> [F][512] bf16 with K PERMUTED to match chunk-major A12:
//     position k: c=k>>6, q=k&63; q<32 -> Wa[.][c*32+q] else Wb[.][c*32+q-32]
__global__ void k_wall(const float* __restrict__ Wn1, const float* __restrict__ Wn2,
                       const float* __restrict__ W11, const float* __restrict__ W12,
                       const float* __restrict__ W21, const float* __restrict__ W22,
                       const float* __restrict__ W31, const float* __restrict__ W32,
                       const float* __restrict__ W41, const float* __restrict__ W42,
                       unsigned short* __restrict__ wn0c, unsigned short* __restrict__ wn1c,
                       unsigned short* __restrict__ wc0, unsigned short* __restrict__ wc1,
                       unsigned short* __restrict__ wc2, unsigned short* __restrict__ wc3,
                       int F, int KC, int KP) {
    int idx = blockIdx.x * 256 + threadIdx.x;
    int npad = F * KP;
    if (idx < 2 * npad) {
        const float* W = (idx < npad) ? Wn1 : Wn2;
        unsigned short* Wc = (idx < npad) ? wn0c : wn1c;
        int t = (idx < npad) ? idx : idx - npad;
        int o = t / KP, k = t - o * KP;
        Wc[t] = f2b(k < KC ? W[(size_t)o * KC + k] : 0.0f);
        return;
    }
    int t = idx - 2 * npad;
    int seg = F * 512;
    if (t >= 4 * seg) return;
    int which = t / seg;
    int r = t - which * seg;
    const float* Wa = (which == 0) ? W11 : (which == 1) ? W21 : (which == 2) ? W31 : W41;
    const float* Wb = (which == 0) ? W12 : (which == 1) ? W22 : (which == 2) ? W32 : W42;
    unsigned short* Wc = (which == 0) ? wc0 : (which == 1) ? wc1 : (which == 2) ? wc2 : wc3;
    int o = r >> 9, k = r & 511;
    int c = k >> 6, q = k & 63;
    float v = (q < 32) ? Wa[(size_t)o * 256 + c * 32 + q]
                       : Wb[(size_t)o * 256 + c * 32 + (q - 32)];
    Wc[r] = f2b(v);
}

// ---------------- chunked CSR gather-aggregation ----------------
// Node features X in chunk-major layout [c][n][32] bf16 (3.2MB slice per chunk
// -> fits one XCD's 4MB L2). chunk = blockIdx.x & 7 pins chunk->XCD via the
// round-robin dispatch heuristic (perf-only assumption). One wave per node:
// lanes split in halves over edges, lane f = feature within chunk.
// Output A [c][n][64] = [a1(32) | a2(32)] per node per chunk.
__global__ __launch_bounds__(256) void k_aggc(
    const unsigned short* __restrict__ X0, const unsigned short* __restrict__ X1,
    const int* __restrict__ off0, const int* __restrict__ off1,
    const unsigned* __restrict__ rec0, const unsigned* __restrict__ rec1,
    const float* __restrict__ dinv0, const float* __restrict__ dinv1,
    unsigned short* __restrict__ A0, unsigned short* __restrict__ A1, int n) {
    const int s = blockIdx.y;
    const unsigned short* X = s ? X1 : X0;
    const int* off = s ? off1 : off0;
    const unsigned* rec = s ? rec1 : rec0;
    const float* dinv = s ? dinv1 : dinv0;
    unsigned short* A = s ? A1 : A0;

    const int c = blockIdx.x & 7;
    const int b = blockIdx.x >> 3;
    const int wave = threadIdx.x >> 6;
    const int lane = threadIdx.x & 63;
    const int half = lane >> 5;
    const int f = lane & 31;
    const int i = b * 4 + wave;
    if (i >= n) return;

    const unsigned short* Xc = X + (size_t)c * n * 32;
    const float di = dinv[i];

    float acc1 = 0.f, acc2 = 0.f;
    if (half == 0) {
        float xi = b2f(Xc[(size_t)i * 32 + f]);     // self loop: deg_norm=di*di, edge_norm=1
        acc1 = di * di * xi;
        acc2 = xi;
    }

    const int e1 = off[i + 1];
    int e = off[i] + half;
    for (; e + 2 < e1; e += 4) {                    // 2 edges per half per iter
        unsigned ra = rec[e], rb = rec[e + 2];
        int ja = ra & 0xFFFF, jb = rb & 0xFFFF;
        float wa2 = h2f((unsigned short)(ra >> 16));
        float wb2 = h2f((unsigned short)(rb >> 16));
        float wa1 = dinv[ja] * di;
        float wb1 = dinv[jb] * di;
        float xa = b2f(Xc[(size_t)ja * 32 + f]);
        float xb = b2f(Xc[(size_t)jb * 32 + f]);
        acc1 += wa1 * xa; acc2 += wa2 * xa;
        acc1 += wb1 * xb; acc2 += wb2 * xb;
    }
    for (; e < e1; e += 2) {
        unsigned ra = rec[e];
        int ja = ra & 0xFFFF;
        float wa2 = h2f((unsigned short)(ra >> 16));
        float wa1 = dinv[ja] * di;
        float xa = b2f(Xc[(size_t)ja * 32 + f]);
        acc1 += wa1 * xa; acc2 += wa2 * xa;
    }

    acc1 += __shfl_xor(acc1, 32);
    acc2 += __shfl_xor(acc2, 32);

    size_t base = ((size_t)c * n + i) * 64;         // wave writes 128B contiguous
    A[base + half * 32 + f] = f2b(half ? acc2 : acc1);
}

// ---------------- bf16 MFMA GEMM (B^T layout) ----------------
// C[M][Nc] = op(A @ B^T). 128x128 tile, BK=32, 4 waves, global_load_lds w=16.
// aChunk: A stored [c][M][64] (c = k>>6, within-block half = (k>>5)&1).
// outChunk: bf16 output stored chunk-major [col>>5][M][32].
#define GLL(g, l) \
    __builtin_amdgcn_global_load_lds((__attribute__((address_space(1))) void*)(g), \
                                     (__attribute__((address_space(3))) void*)(l), 16, 0, 0)

__global__ __launch_bounds__(256) void gemm_bt(
    const unsigned short* __restrict__ A,
    const unsigned short* __restrict__ B0, const unsigned short* __restrict__ B1,
    int M, int K, int Nc,
    float* __restrict__ outF,
    unsigned short* __restrict__ outH0, unsigned short* __restrict__ outH1,
    float alpha, int relu, int accum, int aChunk, int outChunk) {
    const unsigned short* B = blockIdx.z ? B1 : B0;
    unsigned short* outH = blockIdx.z ? outH1 : outH0;

    __shared__ __align__(16) unsigned short sA[128 * 32];
    __shared__ __align__(16) unsigned short sB[128 * 32];
    const int tid = threadIdx.x;
    const int lane = tid & 63;
    const int wave = tid >> 6;
    const int bm = blockIdx.x * 128;
    const int bn = blockIdx.y * 128;

    const int r0 = wave * 32 + (lane >> 2);
    const int kcol = (lane & 3) * 8;
    const int ga0 = min(bm + r0, M - 1);
    const int ga1 = min(bm + r0 + 16, M - 1);
    const int gb0 = min(bn + r0, Nc - 1);
    const int gb1 = min(bn + r0 + 16, Nc - 1);
    const unsigned short* pa0 = A + (size_t)ga0 * K + kcol;
    const unsigned short* pa1 = A + (size_t)ga1 * K + kcol;
    const unsigned short* pb0 = B + (size_t)gb0 * K + kcol;
    const unsigned short* pb1 = B + (size_t)gb1 * K + kcol;
    unsigned short* la0 = &sA[wave * 1024];
    unsigned short* la1 = &sA[wave * 1024 + 512];
    unsigned short* lb0 = &sB[wave * 1024];
    unsigned short* lb1 = &sB[wave * 1024 + 512];

    floatx4 acc[4][4];
    #pragma unroll
    for (int i = 0; i < 4; i++)
        #pragma unroll
        for (int j = 0; j < 4; j++) acc[i][j] = (floatx4){0.f, 0.f, 0.f, 0.f};

    const int mbase = (wave & 1) * 64 + (lane & 15);
    const int nbase = (wave >> 1) * 64 + (lane & 15);
    const int koff = (lane >> 4) * 8;

    for (int kk = 0; kk < K; kk += 32) {
        const unsigned short *qa0, *qa1;
        if (aChunk) {
            size_t boff = ((size_t)(kk >> 6) * M) * 64 + (size_t)(((kk >> 5) & 1) * 32 + kcol);
            qa0 = A + boff + (size_t)ga0 * 64;
            qa1 = A + boff + (size_t)ga1 * 64;
        } else {
            qa0 = pa0 + kk;
            qa1 = pa1 + kk;
        }
        GLL(qa0, la0);
        GLL(qa1, la1);
        GLL(pb0 + kk, lb0);
        GLL(pb1 + kk, lb1);
        __syncthreads();
        bf16x8 af[4], bf[4];
        #pragma unroll
        for (int mi = 0; mi < 4; mi++)
            af[mi] = *(const bf16x8*)&sA[(mbase + mi * 16) * 32 + koff];
        #pragma unroll
        for (int ni = 0; ni < 4; ni++)
            bf[ni] = *(const bf16x8*)&sB[(nbase + ni * 16) * 32 + koff];
        #pragma unroll
        for (int mi = 0; mi < 4; mi++)
            #pragma unroll
            for (int ni = 0; ni < 4; ni++)
                acc[mi][ni] = __builtin_amdgcn_mfma_f32_16x16x32_bf16(
                    af[mi], bf[ni], acc[mi][ni], 0, 0, 0);
        __syncthreads();
    }

    // epilogue: C/D layout col=lane&15, row=(lane>>4)*4+reg  [m89-verified]
    const int crow = bm + (wave & 1) * 64 + (lane >> 4) * 4;
    const int ccol = bn + (wave >> 1) * 64 + (lane & 15);
    #pragma unroll
    for (int mi = 0; mi < 4; mi++) {
        #pragma unroll
        for (int ni = 0; ni < 4; ni++) {
            #pragma unroll
            for (int r = 0; r < 4; r++) {
                int row = crow + mi * 16 + r;
                if (row >= M) continue;
                int col = ccol + ni * 16;
                float v = acc[mi][ni][r];
                if (relu) v = fmaxf(v, 0.0f);
                v *= alpha;
                if (outF) {
                    size_t idx = (size_t)row * Nc + col;
                    outF[idx] = accum ? (outF[idx] + v) : v;
                } else {
                    size_t idx = outChunk
                        ? (((size_t)(col >> 5) * M + row) * 32 + (col & 31))
                        : ((size_t)row * Nc + col);
                    float p = accum ? b2f(outH[idx]) : 0.0f;
                    outH[idx] = f2b(p + v);
                }
            }
        }
    }
}

// ---------------- host orchestration ----------------

extern "C" void kernel_launch(void* const* d_in, const int* in_sizes, int n_in,
                              void* d_out, int out_size, void* d_ws, size_t ws_size,
                              hipStream_t stream) {
    const int F = 256;
    const int N = in_sizes[0] / F;
    const int PEd = in_sizes[1] / N;          // 98
    const int E = in_sizes[2] / 2;            // 800000
    const int KC = F + PEd;                   // 354
    const int KP = (KC + 31) & ~31;           // 384

    const float* x   = (const float*)d_in[0];
    const float* pe  = (const float*)d_in[1];
    const int*   ei0 = (const int*)d_in[2];
    const float* ea0 = (const float*)d_in[3];
    const int*   ei1 = (const int*)d_in[4];
    const float* ea1 = (const float*)d_in[5];
    const float* Wn1 = (const float*)d_in[6];
    const float* Wn2 = (const float*)d_in[7];
    const float* W11 = (const float*)d_in[8];
    const float* W12 = (const float*)d_in[9];
    const float* W21 = (const float*)d_in[10];
    const float* W22 = (const float*)d_in[11];
    const float* W31 = (const float*)d_in[12];
    const float* W32 = (const float*)d_in[13];
    const float* W41 = (const float*)d_in[14];
    const float* W42 = (const float*)d_in[15];
    float* out = (float*)d_out;

    char* p = (char*)d_ws;
    auto alloc = [&](size_t b) -> char* {
        char* r = p;
        p += (b + 255) & ~(size_t)255;
        return r;
    };
    int*   cnt0  = (int*)alloc((size_t)N * 4);
    int*   cnt1  = (int*)alloc((size_t)N * 4);
    int*   off0  = (int*)alloc((size_t)(N + 1) * 4);
    int*   off1  = (int*)alloc((size_t)(N + 1) * 4);
    int*   cur0  = (int*)alloc((size_t)N * 4);
    int*   cur1  = (int*)alloc((size_t)N * 4);
    float* dinv0 = (float*)alloc((size_t)N * 4);
    float* dinv1 = (float*)alloc((size_t)N * 4);
    unsigned* rec0 = (unsigned*)alloc((size_t)E * 4);
    unsigned* rec1 = (unsigned*)alloc((size_t)E * 4);
    unsigned short* wn0c = (unsigned short*)alloc((size_t)F * KP * 2);
    unsigned short* wn1c = (unsigned short*)alloc((size_t)F * KP * 2);
    unsigned short* wc0  = (unsigned short*)alloc((size_t)F * 512 * 2);
    unsigned short* wc1  = (unsigned short*)alloc((size_t)F * 512 * 2);
    unsigned short* wc2  = (unsigned short*)alloc((size_t)F * 512 * 2);
    unsigned short* wc3  = (unsigned short*)alloc((size_t)F * 512 * 2);
    // xa|xb contiguous; their union (N*512 bf16) is reused as layer-2's second
    // aggregation buffer (xa/xb dead by then).
    unsigned short* xa   = (unsigned short*)alloc((size_t)N * 512 * 2);
    unsigned short* xb   = xa + (size_t)N * 256;
    unsigned short* h    = (unsigned short*)alloc((size_t)N * F * 2);
    unsigned short* a12  = (unsigned short*)alloc((size_t)N * 512 * 2);
    unsigned short* xc   = a12;                 // xc dead after node transforms
    unsigned short* a12b = xa;                  // layer-2 second agg output

    const int B = 256;
    const int gE = (E + B - 1) / B;
    const int gN = (N + B - 1) / B;
    const int gAgg = ((N + 3) / 4) * 8;         // 4 nodes/block x 8 chunks
    dim3 gemm_grid((N + 127) / 128, 2);
    dim3 gemm_grid2((N + 127) / 128, 2, 2);

    // 1. degree / dinv / CSR
    hipMemsetAsync(cnt0, 0, (size_t)N * 4, stream);
    hipMemsetAsync(cnt1, 0, (size_t)N * 4, stream);
    k_cnt2<<<dim3(gE, 2), B, 0, stream>>>(ei0 + E, ei1 + E, E, cnt0, cnt1);
    k_scan2<<<dim3(1, 2), 1024, 0, stream>>>(cnt0, cnt1, off0, off1, N);
    k_prep<<<dim3(gN, 2), B, 0, stream>>>(cnt0, cnt1, off0, off1, dinv0, dinv1, cur0, cur1, N);
    k_fill2<<<dim3(gE, 2), B, 0, stream>>>(ei0, ea0, ei1, ea1, E, cur0, cur1, rec0, rec1);

    // 2. bf16 conversions
    k_xc<<<((size_t)N * KP + B - 1) / B, B, 0, stream>>>(x, pe, xc, N, F, PEd, KC, KP);
    {
        int tot = 2 * F * KP + 4 * F * 512;
        k_wall<<<(tot + B - 1) / B, B, 0, stream>>>(Wn1, Wn2, W11, W12, W21, W22,
                                                    W31, W32, W41, W42,
                                                    wn0c, wn1c, wc0, wc1, wc2, wc3,
                                                    F, KC, KP);
    }

    // 3. node transforms -> xa/xb chunk-major
    gemm_bt<<<gemm_grid2, B, 0, stream>>>(xc, wn0c, wn1c, N, KP, F,
                                          nullptr, xa, xb, 1.0f, 0, 0, 0, 1);

    // 4. layer 1: h = 0.5*relu(conv1(agg0(xa))) + 0.5*relu(conv2(agg1(xb)))
    k_aggc<<<dim3(gAgg, 1), B, 0, stream>>>(xa, xa, off0, off0, rec0, rec0,
                                            dinv0, dinv0, a12, a12, N);
    gemm_bt<<<gemm_grid, B, 0, stream>>>(a12, wc0, wc0, N, 512, F,
                                         nullptr, h, h, 0.5f, 1, 0, 1, 1);
    k_aggc<<<dim3(gAgg, 1), B, 0, stream>>>(xb, xb, off1, off1, rec1, rec1,
                                            dinv1, dinv1, a12, a12, N);
    gemm_bt<<<gemm_grid, B, 0, stream>>>(a12, wc1, wc1, N, 512, F,
                                         nullptr, h, h, 0.5f, 1, 1, 1, 1);

    // 5. layer 2: both sets in one dispatch (shared h slice), then out GEMMs
    k_aggc<<<dim3(gAgg, 2), B, 0, stream>>>(h, h, off0, off1, rec0, rec1,
                                            dinv0, dinv1, a12, a12b, N);
    gemm_bt<<<gemm_grid, B, 0, stream>>>(a12, wc2, wc2, N, 512, F,
                                         out, nullptr, nullptr, 0.5f, 1, 0, 1, 0);
    gemm_bt<<<gemm_grid, B, 0, stream>>>(a12b, wc3, wc3, N, 512, F,
                                         out, nullptr, nullptr, 0.5f, 1, 1, 1, 0);
}

// Round 5
// 914.642 us; speedup vs baseline: 1.5478x; 1.5478x over previous
//
#include <hip/hip_runtime.h>

// ---------------------------------------------------------------------------
// GraphTrajSimEncoder on MI355X — round 5.
// R4 post-mortem: feature-chunked agg cut FETCH 379->78MB but was instruction-
// issue bound (8x edge-visit replication, ~210us of VALU issue = 54% of 392us).
// Same L2 line-access count as R2. Revert to one-pass full-row gather with:
//   - half-wave per edge, 16B/lane (2 edges per gather instruction)
//   - 8 edges in flight per wave (4 predicated pairs/group)
//   - 8B CSR record (src, fp16 w1|w2): no dependent dinv gather in hot loop
//   - per-node source-sorted adjacency (bitonic/wave) -> moving-window L2 hits
// ---------------------------------------------------------------------------

using bf16x8  = __attribute__((ext_vector_type(8))) __bf16;
using floatx4 = __attribute__((ext_vector_type(4))) float;

__device__ __forceinline__ float b2f(unsigned short b) {
    return __uint_as_float(((unsigned)b) << 16);
}
__device__ __forceinline__ unsigned short f2b(float f) {
    unsigned u = __float_as_uint(f);
    return (unsigned short)((u + 0x7FFFu + ((u >> 16) & 1u)) >> 16);
}
__device__ __forceinline__ unsigned short f2h(float f) {
    _Float16 h = (_Float16)f;
    return __builtin_bit_cast(unsigned short, h);
}
__device__ __forceinline__ float h2f(unsigned short u) {
    return (float)__builtin_bit_cast(_Float16, u);
}
__device__ __forceinline__ void unpack8(uint4 p, float v[8]) {
    v[0] = __uint_as_float(p.x << 16);
    v[1] = __uint_as_float(p.x & 0xFFFF0000u);
    v[2] = __uint_as_float(p.y << 16);
    v[3] = __uint_as_float(p.y & 0xFFFF0000u);
    v[4] = __uint_as_float(p.z << 16);
    v[5] = __uint_as_float(p.z & 0xFFFF0000u);
    v[6] = __uint_as_float(p.w << 16);
    v[7] = __uint_as_float(p.w & 0xFFFF0000u);
}

// ---------------- graph preprocessing ----------------

__global__ void k_cnt2(const int* __restrict__ col0, const int* __restrict__ col1,
                       int E, int* __restrict__ cnt0, int* __restrict__ cnt1) {
    int e = blockIdx.x * 256 + threadIdx.x;
    const int* col = blockIdx.y ? col1 : col0;
    int* cnt = blockIdx.y ? cnt1 : cnt0;
    if (e < E) atomicAdd(&cnt[col[e]], 1);
}

// grid (1,2): one block scans one set. off[0]=0, off[i+1]=sum(cnt[0..i])
__global__ __launch_bounds__(1024) void k_scan2(
    const int* __restrict__ cnt0, const int* __restrict__ cnt1,
    int* __restrict__ off0, int* __restrict__ off1, int n) {
    const int* cnt = blockIdx.y ? cnt1 : cnt0;
    int* off = blockIdx.y ? off1 : off0;
    __shared__ int wsum[16];
    __shared__ int wpre[16];
    __shared__ int carry;
    const int t = threadIdx.x;
    const int lane = t & 63;
    const int w = t >> 6;
    if (t == 0) { carry = 0; off[0] = 0; }
    __syncthreads();
    for (int base = 0; base < n; base += 1024) {
        int i = base + t;
        int v = (i < n) ? cnt[i] : 0;
        #pragma unroll
        for (int d = 1; d < 64; d <<= 1) {
            int u = __shfl_up(v, d, 64);
            if (lane >= d) v += u;
        }
        if (lane == 63) wsum[w] = v;
        __syncthreads();
        if (t < 16) {
            int s = wsum[t];
            #pragma unroll
            for (int d = 1; d < 16; d <<= 1) {
                int u = __shfl_up(s, d, 16);
                if (t >= d) s += u;
            }
            wpre[t] = s;
        }
        __syncthreads();
        int add = carry + (w > 0 ? wpre[w - 1] : 0);
        if (i < n) off[i + 1] = v + add;
        __syncthreads();
        if (t == 0) carry += wpre[15];
        __syncthreads();
    }
}

// dinv = rsqrt(deg+1) (self loop), cur = off  — grid (gN,2)
__global__ void k_prep(const int* __restrict__ cnt0, const int* __restrict__ cnt1,
                       const int* __restrict__ off0, const int* __restrict__ off1,
                       float* __restrict__ dinv0, float* __restrict__ dinv1,
                       int* __restrict__ cur0, int* __restrict__ cur1, int n) {
    int i = blockIdx.x * 256 + threadIdx.x;
    if (i >= n) return;
    const int* cnt = blockIdx.y ? cnt1 : cnt0;
    const int* off = blockIdx.y ? off1 : off0;
    float* dinv = blockIdx.y ? dinv1 : dinv0;
    int* cur = blockIdx.y ? cur1 : cur0;
    dinv[i] = rsqrtf((float)(cnt[i] + 1));
    cur[i] = off[i];
}

// CSR fill: 8B record per edge = (src:u32, (fp16 w1)<<16 | fp16 w2).
// w1 = dinv[src]*dinv[dst] precomputed here (kills dependent gather in k_agg).
__global__ void k_fill2(const int* __restrict__ ei0, const float* __restrict__ ea0,
                        const int* __restrict__ ei1, const float* __restrict__ ea1,
                        int E, const float* __restrict__ dinv0,
                        const float* __restrict__ dinv1,
                        int* __restrict__ cur0, int* __restrict__ cur1,
                        uint2* __restrict__ rec0, uint2* __restrict__ rec1) {
    int e = blockIdx.x * 256 + threadIdx.x;
    if (e >= E) return;
    const int* ei = blockIdx.y ? ei1 : ei0;
    const float* ea = blockIdx.y ? ea1 : ea0;
    const float* dinv = blockIdx.y ? dinv1 : dinv0;
    int* cur = blockIdx.y ? cur1 : cur0;
    uint2* rec = blockIdx.y ? rec1 : rec0;
    int r = ei[e];          // source
    int c = ei[E + e];      // target
    float a = ea[e];
    float w2 = (a > 0.0f) ? fminf(rsqrtf(a), 1.0f) : 0.0f;
    float w1 = dinv[r] * dinv[c];
    int p = atomicAdd(&cur[c], 1);
    rec[p] = make_uint2((unsigned)r,
                        ((unsigned)f2h(w1) << 16) | (unsigned)f2h(w2));
}

// Per-node bitonic sort of adjacency by (src,w) — perf-only (moving-window L2
// locality for concurrent waves) + makes accumulation order deterministic.
// One wave per node; only nodes with 2..64 edges (Poisson(16): deg>64 ~ never).
__global__ __launch_bounds__(256) void k_sort(
    const int* __restrict__ off0, const int* __restrict__ off1,
    uint2* __restrict__ rec0, uint2* __restrict__ rec1, int n) {
    const int s = blockIdx.y;
    const int* off = s ? off1 : off0;
    uint2* rec = s ? rec1 : rec0;
    const int gw = (blockIdx.x * 256 + threadIdx.x) >> 6;
    const int lane = threadIdx.x & 63;
    if (gw >= n) return;
    const int e0 = off[gw];
    const int cnt = off[gw + 1] - e0;
    if (cnt <= 1 || cnt > 64) return;
    unsigned long long v = ~0ull;
    if (lane < cnt) {
        uint2 r = rec[e0 + lane];
        v = ((unsigned long long)r.x << 32) | (unsigned long long)r.y;
    }
    #pragma unroll
    for (int k = 2; k <= 64; k <<= 1) {
        #pragma unroll
        for (int j = k >> 1; j > 0; j >>= 1) {
            unsigned long long o = __shfl_xor(v, j);
            bool lower = (lane & j) == 0;
            bool up = (lane & k) == 0;
            bool takeMin = (lower == up);
            bool less = v < o;
            v = (takeMin == less) ? v : o;
        }
    }
    if (lane < cnt)
        rec[e0 + lane] = make_uint2((unsigned)(v >> 32), (unsigned)v);
}

// ---------------- dtype conversions ----------------

// xc[i][k] (bf16, K padded to KP): k<F -> x, k<KC -> d2an, else 0  (row-major)
__global__ void k_xc(const float* __restrict__ x, const float* __restrict__ pe,
                     unsigned short* __restrict__ xc, int n, int F, int PEd,
                     int KC, int KP) {
    int idx = blockIdx.x * 256 + threadIdx.x;
    if (idx >= n * KP) return;
    int i = idx / KP, k = idx - i * KP;
    float v = 0.0f;
    if (k < F)        v = x[(size_t)i * F + k];
    else if (k < KC)  v = pe[(size_t)i * PEd + (k - F)];
    xc[idx] = f2b(v);
}

// weight conversions (row-major K):
//   seg 0/1: Wn [F][KC] f32 -> [F][KP] bf16 zero-padded
//   seg 2..5: [Wa|Wb] pairs -> [F][512] bf16 plain concat
__global__ void k_wall(const float* __restrict__ Wn1, const float* __restrict__ Wn2,
                       const float* __restrict__ W11, const float* __restrict__ W12,
                       const float* __restrict__ W21, const float* __restrict__ W22,
                       const float* __restrict__ W31, const float* __restrict__ W32,
                       const float* __restrict__ W41, const float* __restrict__ W42,
                       unsigned short* __restrict__ wn0c, unsigned short* __restrict__ wn1c,
                       unsigned short* __restrict__ wc0, unsigned short* __restrict__ wc1,
                       unsigned short* __restrict__ wc2, unsigned short* __restrict__ wc3,
                       int F, int KC, int KP) {
    int idx = blockIdx.x * 256 + threadIdx.x;
    int npad = F * KP;
    if (idx < 2 * npad) {
        const float* W = (idx < npad) ? Wn1 : Wn2;
        unsigned short* Wc = (idx < npad) ? wn0c : wn1c;
        int t = (idx < npad) ? idx : idx - npad;
        int o = t / KP, k = t - o * KP;
        Wc[t] = f2b(k < KC ? W[(size_t)o * KC + k] : 0.0f);
        return;
    }
    int t = idx - 2 * npad;
    int seg = F * 512;
    if (t >= 4 * seg) return;
    int which = t / seg;
    int r = t - which * seg;
    const float* Wa = (which == 0) ? W11 : (which == 1) ? W21 : (which == 2) ? W31 : W41;
    const float* Wb = (which == 0) ? W12 : (which == 1) ? W22 : (which == 2) ? W32 : W42;
    unsigned short* Wc = (which == 0) ? wc0 : (which == 1) ? wc1 : (which == 2) ? wc2 : wc3;
    int o = r >> 9, k = r & 511;
    float v = (k < 256) ? Wa[(size_t)o * 256 + k] : Wb[(size_t)o * 256 + (k - 256)];
    Wc[r] = f2b(v);
}

// ---------------- CSR gather-aggregation ----------------
// One wave per node. Half-wave per edge: lanes 0-31 handle even-offset edges,
// 32-63 odd; each lane covers 8 features (16B uint4 load -> 2 edges per gather
// instruction, 512B/edge). 4 pairs (8 edges) in flight per group; invalid tail
// slots gather cached row 0 with zero weights. Cross-half reduce via shfl_xor,
// self-loop added post-reduction. Output A[i] = [a1(256)|a2(256)] bf16.
__global__ __launch_bounds__(256) void k_agg(
    const unsigned short* __restrict__ X0, const unsigned short* __restrict__ X1,
    const int* __restrict__ off0, const int* __restrict__ off1,
    const uint2* __restrict__ rec0, const uint2* __restrict__ rec1,
    const float* __restrict__ dinv0, const float* __restrict__ dinv1,
    unsigned short* __restrict__ A0, unsigned short* __restrict__ A1, int n) {
    const int s = blockIdx.y;
    const unsigned short* X = s ? X1 : X0;
    const int* off = s ? off1 : off0;
    const uint2* rec = s ? rec1 : rec0;
    const float* dinv = s ? dinv1 : dinv0;
    unsigned short* A = s ? A1 : A0;

    const int gw = (blockIdx.x * 256 + threadIdx.x) >> 6;
    const int lane = threadIdx.x & 63;
    if (gw >= n) return;
    const int half = lane >> 5;
    const int f8 = lane & 31;

    const float di = dinv[gw];
    uint4 xs = *(const uint4*)(X + (size_t)gw * 256 + f8 * 8);   // self row

    float acc1[8], acc2[8];
    #pragma unroll
    for (int j = 0; j < 8; j++) { acc1[j] = 0.f; acc2[j] = 0.f; }

    const int e0 = off[gw], e1 = off[gw + 1];
    for (int base = e0; base < e1; base += 8) {
        uint2 r[4];
        #pragma unroll
        for (int k = 0; k < 4; k++) {
            int ie = base + 2 * k + half;
            int ic = ie < e1 ? ie : e1 - 1;
            uint2 rr = rec[ic];
            if (ie >= e1) { rr.x = 0u; rr.y = 0u; }   // row 0 (cached), zero weight
            r[k] = rr;
        }
        uint4 xg[4];
        #pragma unroll
        for (int k = 0; k < 4; k++)
            xg[k] = *(const uint4*)(X + (size_t)r[k].x * 256 + f8 * 8);
        #pragma unroll
        for (int k = 0; k < 4; k++) {
            float w1 = h2f((unsigned short)(r[k].y >> 16));
            float w2 = h2f((unsigned short)(r[k].y & 0xFFFFu));
            float v[8];
            unpack8(xg[k], v);
            #pragma unroll
            for (int j = 0; j < 8; j++) {
                acc1[j] += w1 * v[j];
                acc2[j] += w2 * v[j];
            }
        }
    }

    #pragma unroll
    for (int j = 0; j < 8; j++) {
        acc1[j] += __shfl_xor(acc1[j], 32);
        acc2[j] += __shfl_xor(acc2[j], 32);
    }

    float vs[8];
    unpack8(xs, vs);
    const float wself = half ? 1.0f : di * di;   // a2 self weight 1, a1 = di^2
    unsigned short o[8];
    #pragma unroll
    for (int j = 0; j < 8; j++) {
        float rv = (half ? acc2[j] : acc1[j]) + wself * vs[j];
        o[j] = f2b(rv);
    }
    uint4 q;
    q.x = (unsigned)o[0] | ((unsigned)o[1] << 16);
    q.y = (unsigned)o[2] | ((unsigned)o[3] << 16);
    q.z = (unsigned)o[4] | ((unsigned)o[5] << 16);
    q.w = (unsigned)o[6] | ((unsigned)o[7] << 16);
    *(uint4*)(A + (size_t)gw * 512 + half * 256 + f8 * 8) = q;
}

// ---------------- bf16 MFMA GEMM (B^T layout) ----------------
// C[M][Nc] = op(A[M][K] @ B[Nc][K]^T). 128x128 tile, BK=32, 4 waves,
// global_load_lds width-16 staging (m97). blockIdx.z selects (B,outH).
#define GLL(g, l) \
    __builtin_amdgcn_global_load_lds((__attribute__((address_space(1))) void*)(g), \
                                     (__attribute__((address_space(3))) void*)(l), 16, 0, 0)

__global__ __launch_bounds__(256) void gemm_bt(
    const unsigned short* __restrict__ A,
    const unsigned short* __restrict__ B0, const unsigned short* __restrict__ B1,
    int M, int K, int Nc,
    float* __restrict__ outF,
    unsigned short* __restrict__ outH0, unsigned short* __restrict__ outH1,
    float alpha, int relu, int accum) {
    const unsigned short* B = blockIdx.z ? B1 : B0;
    unsigned short* outH = blockIdx.z ? outH1 : outH0;

    __shared__ __align__(16) unsigned short sA[128 * 32];
    __shared__ __align__(16) unsigned short sB[128 * 32];
    const int tid = threadIdx.x;
    const int lane = tid & 63;
    const int wave = tid >> 6;
    const int bm = blockIdx.x * 128;
    const int bn = blockIdx.y * 128;

    const int r0 = wave * 32 + (lane >> 2);
    const int kcol = (lane & 3) * 8;
    const int ga0 = min(bm + r0, M - 1);
    const int ga1 = min(bm + r0 + 16, M - 1);
    const int gb0 = min(bn + r0, Nc - 1);
    const int gb1 = min(bn + r0 + 16, Nc - 1);
    const unsigned short* pa0 = A + (size_t)ga0 * K + kcol;
    const unsigned short* pa1 = A + (size_t)ga1 * K + kcol;
    const unsigned short* pb0 = B + (size_t)gb0 * K + kcol;
    const unsigned short* pb1 = B + (size_t)gb1 * K + kcol;
    unsigned short* la0 = &sA[wave * 1024];
    unsigned short* la1 = &sA[wave * 1024 + 512];
    unsigned short* lb0 = &sB[wave * 1024];
    unsigned short* lb1 = &sB[wave * 1024 + 512];

    floatx4 acc[4][4];
    #pragma unroll
    for (int i = 0; i < 4; i++)
        #pragma unroll
        for (int j = 0; j < 4; j++) acc[i][j] = (floatx4){0.f, 0.f, 0.f, 0.f};

    const int mbase = (wave & 1) * 64 + (lane & 15);
    const int nbase = (wave >> 1) * 64 + (lane & 15);
    const int koff = (lane >> 4) * 8;

    for (int kk = 0; kk < K; kk += 32) {
        GLL(pa0 + kk, la0);
        GLL(pa1 + kk, la1);
        GLL(pb0 + kk, lb0);
        GLL(pb1 + kk, lb1);
        __syncthreads();
        bf16x8 af[4], bf[4];
        #pragma unroll
        for (int mi = 0; mi < 4; mi++)
            af[mi] = *(const bf16x8*)&sA[(mbase + mi * 16) * 32 + koff];
        #pragma unroll
        for (int ni = 0; ni < 4; ni++)
            bf[ni] = *(const bf16x8*)&sB[(nbase + ni * 16) * 32 + koff];
        #pragma unroll
        for (int mi = 0; mi < 4; mi++)
            #pragma unroll
            for (int ni = 0; ni < 4; ni++)
                acc[mi][ni] = __builtin_amdgcn_mfma_f32_16x16x32_bf16(
                    af[mi], bf[ni], acc[mi][ni], 0, 0, 0);
        __syncthreads();
    }

    // epilogue: C/D layout col=lane&15, row=(lane>>4)*4+reg  [m89-verified]
    const int crow = bm + (wave & 1) * 64 + (lane >> 4) * 4;
    const int ccol = bn + (wave >> 1) * 64 + (lane & 15);
    #pragma unroll
    for (int mi = 0; mi < 4; mi++) {
        #pragma unroll
        for (int ni = 0; ni < 4; ni++) {
            #pragma unroll
            for (int r = 0; r < 4; r++) {
                int row = crow + mi * 16 + r;
                if (row >= M) continue;
                int col = ccol + ni * 16;
                float v = acc[mi][ni][r];
                if (relu) v = fmaxf(v, 0.0f);
                v *= alpha;
                size_t idx = (size_t)row * Nc + col;
                if (outF) {
                    outF[idx] = accum ? (outF[idx] + v) : v;
                } else {
                    float p = accum ? b2f(outH[idx]) : 0.0f;
                    outH[idx] = f2b(p + v);
                }
            }
        }
    }
}

// ---------------- host orchestration ----------------

extern "C" void kernel_launch(void* const* d_in, const int* in_sizes, int n_in,
                              void* d_out, int out_size, void* d_ws, size_t ws_size,
                              hipStream_t stream) {
    const int F = 256;
    const int N = in_sizes[0] / F;
    const int PEd = in_sizes[1] / N;          // 98
    const int E = in_sizes[2] / 2;            // 800000
    const int KC = F + PEd;                   // 354
    const int KP = (KC + 31) & ~31;           // 384

    const float* x   = (const float*)d_in[0];
    const float* pe  = (const float*)d_in[1];
    const int*   ei0 = (const int*)d_in[2];
    const float* ea0 = (const float*)d_in[3];
    const int*   ei1 = (const int*)d_in[4];
    const float* ea1 = (const float*)d_in[5];
    const float* Wn1 = (const float*)d_in[6];
    const float* Wn2 = (const float*)d_in[7];
    const float* W11 = (const float*)d_in[8];
    const float* W12 = (const float*)d_in[9];
    const float* W21 = (const float*)d_in[10];
    const float* W22 = (const float*)d_in[11];
    const float* W31 = (const float*)d_in[12];
    const float* W32 = (const float*)d_in[13];
    const float* W41 = (const float*)d_in[14];
    const float* W42 = (const float*)d_in[15];
    float* out = (float*)d_out;

    char* p = (char*)d_ws;
    auto alloc = [&](size_t b) -> char* {
        char* r = p;
        p += (b + 255) & ~(size_t)255;
        return r;
    };
    int*   cnt0  = (int*)alloc((size_t)N * 4);
    int*   cnt1  = (int*)alloc((size_t)N * 4);
    int*   off0  = (int*)alloc((size_t)(N + 1) * 4);
    int*   off1  = (int*)alloc((size_t)(N + 1) * 4);
    int*   cur0  = (int*)alloc((size_t)N * 4);
    int*   cur1  = (int*)alloc((size_t)N * 4);
    float* dinv0 = (float*)alloc((size_t)N * 4);
    float* dinv1 = (float*)alloc((size_t)N * 4);
    uint2* rec0  = (uint2*)alloc((size_t)E * 8);
    uint2* rec1  = (uint2*)alloc((size_t)E * 8);
    unsigned short* wn0c = (unsigned short*)alloc((size_t)F * KP * 2);
    unsigned short* wn1c = (unsigned short*)alloc((size_t)F * KP * 2);
    unsigned short* wc0  = (unsigned short*)alloc((size_t)F * 512 * 2);
    unsigned short* wc1  = (unsigned short*)alloc((size_t)F * 512 * 2);
    unsigned short* wc2  = (unsigned short*)alloc((size_t)F * 512 * 2);
    unsigned short* wc3  = (unsigned short*)alloc((size_t)F * 512 * 2);
    // xa|xb contiguous; reused as layer-2's second agg buffer (dead by then).
    unsigned short* xa   = (unsigned short*)alloc((size_t)N * 512 * 2);
    unsigned short* xb   = xa + (size_t)N * 256;
    unsigned short* h    = (unsigned short*)alloc((size_t)N * F * 2);
    unsigned short* a12  = (unsigned short*)alloc((size_t)N * 512 * 2);
    unsigned short* xc   = a12;                 // xc dead after node transforms
    unsigned short* a12b = xa;                  // layer-2 second agg output

    const int B = 256;
    const int gE = (E + B - 1) / B;
    const int gN = (N + B - 1) / B;
    const int gW = (N + 3) / 4;                 // 4 waves (nodes) per block
    dim3 gemm_grid((N + 127) / 128, 2);
    dim3 gemm_grid2((N + 127) / 128, 2, 2);

    // 1. degree / dinv / CSR / sort
    hipMemsetAsync(cnt0, 0, (size_t)N * 4, stream);
    hipMemsetAsync(cnt1, 0, (size_t)N * 4, stream);
    k_cnt2<<<dim3(gE, 2), B, 0, stream>>>(ei0 + E, ei1 + E, E, cnt0, cnt1);
    k_scan2<<<dim3(1, 2), 1024, 0, stream>>>(cnt0, cnt1, off0, off1, N);
    k_prep<<<dim3(gN, 2), B, 0, stream>>>(cnt0, cnt1, off0, off1, dinv0, dinv1, cur0, cur1, N);
    k_fill2<<<dim3(gE, 2), B, 0, stream>>>(ei0, ea0, ei1, ea1, E, dinv0, dinv1,
                                           cur0, cur1, rec0, rec1);
    k_sort<<<dim3(gW, 2), B, 0, stream>>>(off0, off1, rec0, rec1, N);

    // 2. bf16 conversions
    k_xc<<<((size_t)N * KP + B - 1) / B, B, 0, stream>>>(x, pe, xc, N, F, PEd, KC, KP);
    {
        int tot = 2 * F * KP + 4 * F * 512;
        k_wall<<<(tot + B - 1) / B, B, 0, stream>>>(Wn1, Wn2, W11, W12, W21, W22,
                                                    W31, W32, W41, W42,
                                                    wn0c, wn1c, wc0, wc1, wc2, wc3,
                                                    F, KC, KP);
    }

    // 3. node transforms (both in one dispatch via blockIdx.z)
    gemm_bt<<<gemm_grid2, B, 0, stream>>>(xc, wn0c, wn1c, N, KP, F,
                                          nullptr, xa, xb, 1.0f, 0, 0);

    // 4. layer 1: h = 0.5*relu(conv1(agg0(xa))) + 0.5*relu(conv2(agg1(xb)))
    k_agg<<<dim3(gW, 1), B, 0, stream>>>(xa, xa, off0, off0, rec0, rec0,
                                         dinv0, dinv0, a12, a12, N);
    gemm_bt<<<gemm_grid, B, 0, stream>>>(a12, wc0, wc0, N, 512, F,
                                         nullptr, h, h, 0.5f, 1, 0);
    k_agg<<<dim3(gW, 1), B, 0, stream>>>(xb, xb, off1, off1, rec1, rec1,
                                         dinv1, dinv1, a12, a12, N);
    gemm_bt<<<gemm_grid, B, 0, stream>>>(a12, wc1, wc1, N, 512, F,
                                         nullptr, h, h, 0.5f, 1, 1);

    // 5. layer 2: both sets in one dispatch (shared h table), then out GEMMs
    k_agg<<<dim3(gW, 2), B, 0, stream>>>(h, h, off0, off1, rec0, rec1,
                                         dinv0, dinv1, a12, a12b, N);
    gemm_bt<<<gemm_grid, B, 0, stream>>>(a12, wc2, wc2, N, 512, F,
                                         out, nullptr, nullptr, 0.5f, 1, 0);
    gemm_bt<<<gemm_grid, B, 0, stream>>>(a12b, wc3, wc3, N, 512, F,
                                         out, nullptr, nullptr, 0.5f, 1, 1);
}

// Round 6
// 783.023 us; speedup vs baseline: 1.8080x; 1.1681x over previous
//
#include <hip/hip_runtime.h>

// ---------------------------------------------------------------------------
// GraphTrajSimEncoder on MI355X — round 6.
// R5 post-mortem: sort useless (FETCH unchanged 377MB — no locality to find in
// a random graph); k_agg half-VALU (55%) half-memory. Changes:
//  - scalarized agg: full-wave/edge, uniform (scalar-path) record loads,
//    readfirstlane'd row base (saddr gathers), CSR padded to 8 -> no tail code
//  - layer-1 aggs fused into one dispatch (2nd buffer overlays d_out)
//  - dual-GEMM: 0.5*relu(A0B0^T)+0.5*relu(A1B1^T) in one kernel (pass-0 relu
//    parked in VGPRs) -> kills 2 dispatches + h/out RMW traffic
// ---------------------------------------------------------------------------

using bf16x8  = __attribute__((ext_vector_type(8))) __bf16;
using floatx4 = __attribute__((ext_vector_type(4))) float;

__device__ __forceinline__ float b2f(unsigned short b) {
    return __uint_as_float(((unsigned)b) << 16);
}
__device__ __forceinline__ unsigned short f2b(float f) {
    unsigned u = __float_as_uint(f);
    return (unsigned short)((u + 0x7FFFu + ((u >> 16) & 1u)) >> 16);
}
__device__ __forceinline__ unsigned short f2h(float f) {
    _Float16 h = (_Float16)f;
    return __builtin_bit_cast(unsigned short, h);
}
__device__ __forceinline__ float h2f(unsigned short u) {
    return (float)__builtin_bit_cast(_Float16, u);
}

// ---------------- graph preprocessing ----------------

__global__ void k_cnt2(const int* __restrict__ col0, const int* __restrict__ col1,
                       int E, int* __restrict__ cnt0, int* __restrict__ cnt1) {
    int e = blockIdx.x * 256 + threadIdx.x;
    const int* col = blockIdx.y ? col1 : col0;
    int* cnt = blockIdx.y ? cnt1 : cnt0;
    if (e < E) atomicAdd(&cnt[col[e]], 1);
}

// grid (1,2): scan of PADDED counts (round up to 8): off[0]=0, off[i+1]=sum.
__global__ __launch_bounds__(1024) void k_scan2(
    const int* __restrict__ cnt0, const int* __restrict__ cnt1,
    int* __restrict__ off0, int* __restrict__ off1, int n) {
    const int* cnt = blockIdx.y ? cnt1 : cnt0;
    int* off = blockIdx.y ? off1 : off0;
    __shared__ int wsum[16];
    __shared__ int wpre[16];
    __shared__ int carry;
    const int t = threadIdx.x;
    const int lane = t & 63;
    const int w = t >> 6;
    if (t == 0) { carry = 0; off[0] = 0; }
    __syncthreads();
    for (int base = 0; base < n; base += 1024) {
        int i = base + t;
        int v = (i < n) ? ((cnt[i] + 7) & ~7) : 0;   // pad each node to x8
        #pragma unroll
        for (int d = 1; d < 64; d <<= 1) {
            int u = __shfl_up(v, d, 64);
            if (lane >= d) v += u;
        }
        if (lane == 63) wsum[w] = v;
        __syncthreads();
        if (t < 16) {
            int s = wsum[t];
            #pragma unroll
            for (int d = 1; d < 16; d <<= 1) {
                int u = __shfl_up(s, d, 16);
                if (t >= d) s += u;
            }
            wpre[t] = s;
        }
        __syncthreads();
        int add = carry + (w > 0 ? wpre[w - 1] : 0);
        if (i < n) off[i + 1] = v + add;
        __syncthreads();
        if (t == 0) carry += wpre[15];
        __syncthreads();
    }
}

// dinv = rsqrt(REAL deg + 1), cur = off  — grid (gN,2)
__global__ void k_prep(const int* __restrict__ cnt0, const int* __restrict__ cnt1,
                       const int* __restrict__ off0, const int* __restrict__ off1,
                       float* __restrict__ dinv0, float* __restrict__ dinv1,
                       int* __restrict__ cur0, int* __restrict__ cur1, int n) {
    int i = blockIdx.x * 256 + threadIdx.x;
    if (i >= n) return;
    const int* cnt = blockIdx.y ? cnt1 : cnt0;
    const int* off = blockIdx.y ? off1 : off0;
    float* dinv = blockIdx.y ? dinv1 : dinv0;
    int* cur = blockIdx.y ? cur1 : cur0;
    dinv[i] = rsqrtf((float)(cnt[i] + 1));
    cur[i] = off[i];
}

// CSR fill: 8B record per edge = (src:u32, (fp16 w1)<<16 | fp16 w2).
__global__ void k_fill2(const int* __restrict__ ei0, const float* __restrict__ ea0,
                        const int* __restrict__ ei1, const float* __restrict__ ea1,
                        int E, const float* __restrict__ dinv0,
                        const float* __restrict__ dinv1,
                        int* __restrict__ cur0, int* __restrict__ cur1,
                        uint2* __restrict__ rec0, uint2* __restrict__ rec1) {
    int e = blockIdx.x * 256 + threadIdx.x;
    if (e >= E) return;
    const int* ei = blockIdx.y ? ei1 : ei0;
    const float* ea = blockIdx.y ? ea1 : ea0;
    const float* dinv = blockIdx.y ? dinv1 : dinv0;
    int* cur = blockIdx.y ? cur1 : cur0;
    uint2* rec = blockIdx.y ? rec1 : rec0;
    int r = ei[e];          // source
    int c = ei[E + e];      // target
    float a = ea[e];
    float w2 = (a > 0.0f) ? fminf(rsqrtf(a), 1.0f) : 0.0f;
    float w1 = dinv[r] * dinv[c];
    int p = atomicAdd(&cur[c], 1);
    rec[p] = make_uint2((unsigned)r,
                        ((unsigned)f2h(w1) << 16) | (unsigned)f2h(w2));
}

// pad tail slots with (row 0, zero weights) — grid (gN,2)
__global__ void k_pad(const int* __restrict__ cnt0, const int* __restrict__ cnt1,
                      const int* __restrict__ off0, const int* __restrict__ off1,
                      uint2* __restrict__ rec0, uint2* __restrict__ rec1, int n) {
    int i = blockIdx.x * 256 + threadIdx.x;
    if (i >= n) return;
    const int* cnt = blockIdx.y ? cnt1 : cnt0;
    const int* off = blockIdx.y ? off1 : off0;
    uint2* rec = blockIdx.y ? rec1 : rec0;
    int p = off[i] + cnt[i], pe = off[i + 1];
    for (; p < pe; ++p) rec[p] = make_uint2(0u, 0u);
}

// ---------------- dtype conversions ----------------

// xc[i][k] (bf16, K padded to KP): k<F -> x, k<KC -> d2an, else 0  (row-major)
__global__ void k_xc(const float* __restrict__ x, const float* __restrict__ pe,
                     unsigned short* __restrict__ xc, int n, int F, int PEd,
                     int KC, int KP) {
    int idx = blockIdx.x * 256 + threadIdx.x;
    if (idx >= n * KP) return;
    int i = idx / KP, k = idx - i * KP;
    float v = 0.0f;
    if (k < F)        v = x[(size_t)i * F + k];
    else if (k < KC)  v = pe[(size_t)i * PEd + (k - F)];
    xc[idx] = f2b(v);
}

// weight conversions (row-major K):
//   seg 0/1: Wn [F][KC] f32 -> [F][KP] bf16 zero-padded
//   seg 2..5: [Wa|Wb] pairs -> [F][512] bf16 plain concat
__global__ void k_wall(const float* __restrict__ Wn1, const float* __restrict__ Wn2,
                       const float* __restrict__ W11, const float* __restrict__ W12,
                       const float* __restrict__ W21, const float* __restrict__ W22,
                       const float* __restrict__ W31, const float* __restrict__ W32,
                       const float* __restrict__ W41, const float* __restrict__ W42,
                       unsigned short* __restrict__ wn0c, unsigned short* __restrict__ wn1c,
                       unsigned short* __restrict__ wc0, unsigned short* __restrict__ wc1,
                       unsigned short* __restrict__ wc2, unsigned short* __restrict__ wc3,
                       int F, int KC, int KP) {
    int idx = blockIdx.x * 256 + threadIdx.x;
    int npad = F * KP;
    if (idx < 2 * npad) {
        const float* W = (idx < npad) ? Wn1 : Wn2;
        unsigned short* Wc = (idx < npad) ? wn0c : wn1c;
        int t = (idx < npad) ? idx : idx - npad;
        int o = t / KP, k = t - o * KP;
        Wc[t] = f2b(k < KC ? W[(size_t)o * KC + k] : 0.0f);
        return;
    }
    int t = idx - 2 * npad;
    int seg = F * 512;
    if (t >= 4 * seg) return;
    int which = t / seg;
    int r = t - which * seg;
    const float* Wa = (which == 0) ? W11 : (which == 1) ? W21 : (which == 2) ? W31 : W41;
    const float* Wb = (which == 0) ? W12 : (which == 1) ? W22 : (which == 2) ? W32 : W42;
    unsigned short* Wc = (which == 0) ? wc0 : (which == 1) ? wc1 : (which == 2) ? wc2 : wc3;
    int o = r >> 9, k = r & 511;
    float v = (k < 256) ? Wa[(size_t)o * 256 + k] : Wb[(size_t)o * 256 + (k - 256)];
    Wc[r] = f2b(v);
}

// ---------------- CSR gather-aggregation (scalarized) ----------------
// One wave per node, full wave per edge: lane covers 4 features (uint2, 8B).
// Records are wave-uniform -> uniform loads; row base readfirstlane'd to SGPR
// (saddr gathers, no per-lane 64-bit addr math). CSR padded to x8: no tails.
// Output A[i] = [a1(256) | a2(256)] bf16.
__global__ __launch_bounds__(256) void k_agg(
    const unsigned short* __restrict__ X0, const unsigned short* __restrict__ X1,
    const int* __restrict__ off0, const int* __restrict__ off1,
    const uint2* __restrict__ rec0, const uint2* __restrict__ rec1,
    const float* __restrict__ dinv0, const float* __restrict__ dinv1,
    unsigned short* __restrict__ A0, unsigned short* __restrict__ A1, int n) {
    const int s = blockIdx.y;
    const unsigned short* X = s ? X1 : X0;
    const int* off = s ? off1 : off0;
    const uint2* rec = s ? rec1 : rec0;
    const float* dinv = s ? dinv1 : dinv0;
    unsigned short* A = s ? A1 : A0;

    const int gw = (blockIdx.x * 256 + threadIdx.x) >> 6;
    const int lane = threadIdx.x & 63;
    if (gw >= n) return;

    const int e0 = __builtin_amdgcn_readfirstlane(off[gw]);
    const int e1 = __builtin_amdgcn_readfirstlane(off[gw + 1]);
    const float di = dinv[gw];
    const uint2* X2 = (const uint2*)X;               // 4 bf16 per uint2
    uint2 xs = X2[(size_t)gw * 64 + lane];           // self row

    float acc1[4] = {0.f, 0.f, 0.f, 0.f};
    float acc2[4] = {0.f, 0.f, 0.f, 0.f};

    for (int base = e0; base < e1; base += 8) {
        uint2 rr[8];
        #pragma unroll
        for (int k = 0; k < 8; k++) rr[k] = rec[base + k];   // uniform
        uint2 g[8];
        #pragma unroll
        for (int k = 0; k < 8; k++) {
            unsigned src = (unsigned)__builtin_amdgcn_readfirstlane(rr[k].x);
            g[k] = X2[(size_t)src * 64 + lane];              // saddr gather
        }
        #pragma unroll
        for (int k = 0; k < 8; k++) {
            float w1 = h2f((unsigned short)(rr[k].y >> 16));
            float w2 = h2f((unsigned short)(rr[k].y & 0xFFFFu));
            float v0 = __uint_as_float(g[k].x << 16);
            float v1 = __uint_as_float(g[k].x & 0xFFFF0000u);
            float v2 = __uint_as_float(g[k].y << 16);
            float v3 = __uint_as_float(g[k].y & 0xFFFF0000u);
            acc1[0] += w1 * v0; acc1[1] += w1 * v1; acc1[2] += w1 * v2; acc1[3] += w1 * v3;
            acc2[0] += w2 * v0; acc2[1] += w2 * v1; acc2[2] += w2 * v2; acc2[3] += w2 * v3;
        }
    }

    // self loop: deg_norm = di*di, edge_norm = 1
    {
        float v0 = __uint_as_float(xs.x << 16);
        float v1 = __uint_as_float(xs.x & 0xFFFF0000u);
        float v2 = __uint_as_float(xs.y << 16);
        float v3 = __uint_as_float(xs.y & 0xFFFF0000u);
        float ws = di * di;
        acc1[0] += ws * v0; acc1[1] += ws * v1; acc1[2] += ws * v2; acc1[3] += ws * v3;
        acc2[0] += v0;      acc2[1] += v1;      acc2[2] += v2;      acc2[3] += v3;
    }

    uint2 o1, o2;
    o1.x = (unsigned)f2b(acc1[0]) | ((unsigned)f2b(acc1[1]) << 16);
    o1.y = (unsigned)f2b(acc1[2]) | ((unsigned)f2b(acc1[3]) << 16);
    o2.x = (unsigned)f2b(acc2[0]) | ((unsigned)f2b(acc2[1]) << 16);
    o2.y = (unsigned)f2b(acc2[2]) | ((unsigned)f2b(acc2[3]) << 16);
    *(uint2*)(A + (size_t)gw * 512 + lane * 4) = o1;
    *(uint2*)(A + (size_t)gw * 512 + 256 + lane * 4) = o2;
}

// ---------------- bf16 MFMA GEMM kernels ----------------
#define GLL(g, l) \
    __builtin_amdgcn_global_load_lds((__attribute__((address_space(1))) void*)(g), \
                                     (__attribute__((address_space(3))) void*)(l), 16, 0, 0)

// node-transform GEMM: C[M][Nc] = A[M][K] @ B[Nc][K]^T, bf16 out, z selects B/out.
__global__ __launch_bounds__(256) void gemm_bt(
    const unsigned short* __restrict__ A,
    const unsigned short* __restrict__ B0, const unsigned short* __restrict__ B1,
    int M, int K, int Nc,
    unsigned short* __restrict__ outH0, unsigned short* __restrict__ outH1) {
    const unsigned short* B = blockIdx.z ? B1 : B0;
    unsigned short* outH = blockIdx.z ? outH1 : outH0;

    __shared__ __align__(16) unsigned short sA[128 * 32];
    __shared__ __align__(16) unsigned short sB[128 * 32];
    const int tid = threadIdx.x;
    const int lane = tid & 63;
    const int wave = tid >> 6;
    const int bm = blockIdx.x * 128;
    const int bn = blockIdx.y * 128;

    const int r0 = wave * 32 + (lane >> 2);
    const int kcol = (lane & 3) * 8;
    const int ga0 = min(bm + r0, M - 1);
    const int ga1 = min(bm + r0 + 16, M - 1);
    const int gb0 = min(bn + r0, Nc - 1);
    const int gb1 = min(bn + r0 + 16, Nc - 1);
    const unsigned short* pa0 = A + (size_t)ga0 * K + kcol;
    const unsigned short* pa1 = A + (size_t)ga1 * K + kcol;
    const unsigned short* pb0 = B + (size_t)gb0 * K + kcol;
    const unsigned short* pb1 = B + (size_t)gb1 * K + kcol;
    unsigned short* la0 = &sA[wave * 1024];
    unsigned short* la1 = &sA[wave * 1024 + 512];
    unsigned short* lb0 = &sB[wave * 1024];
    unsigned short* lb1 = &sB[wave * 1024 + 512];

    floatx4 acc[4][4];
    #pragma unroll
    for (int i = 0; i < 4; i++)
        #pragma unroll
        for (int j = 0; j < 4; j++) acc[i][j] = (floatx4){0.f, 0.f, 0.f, 0.f};

    const int mbase = (wave & 1) * 64 + (lane & 15);
    const int nbase = (wave >> 1) * 64 + (lane & 15);
    const int koff = (lane >> 4) * 8;

    for (int kk = 0; kk < K; kk += 32) {
        GLL(pa0 + kk, la0);
        GLL(pa1 + kk, la1);
        GLL(pb0 + kk, lb0);
        GLL(pb1 + kk, lb1);
        __syncthreads();
        bf16x8 af[4], bf[4];
        #pragma unroll
        for (int mi = 0; mi < 4; mi++)
            af[mi] = *(const bf16x8*)&sA[(mbase + mi * 16) * 32 + koff];
        #pragma unroll
        for (int ni = 0; ni < 4; ni++)
            bf[ni] = *(const bf16x8*)&sB[(nbase + ni * 16) * 32 + koff];
        #pragma unroll
        for (int mi = 0; mi < 4; mi++)
            #pragma unroll
            for (int ni = 0; ni < 4; ni++)
                acc[mi][ni] = __builtin_amdgcn_mfma_f32_16x16x32_bf16(
                    af[mi], bf[ni], acc[mi][ni], 0, 0, 0);
        __syncthreads();
    }

    const int crow = bm + (wave & 1) * 64 + (lane >> 4) * 4;
    const int ccol = bn + (wave >> 1) * 64 + (lane & 15);
    #pragma unroll
    for (int mi = 0; mi < 4; mi++)
        #pragma unroll
        for (int ni = 0; ni < 4; ni++)
            #pragma unroll
            for (int r = 0; r < 4; r++) {
                int row = crow + mi * 16 + r;
                if (row >= M) continue;
                int col = ccol + ni * 16;
                outH[(size_t)row * Nc + col] = f2b(acc[mi][ni][r]);
            }
}

// dual GEMM: C = 0.5*relu(A0@B0^T) + 0.5*relu(A1@B1^T); out f32 or bf16.
__global__ __launch_bounds__(256) void gemm_dual(
    const unsigned short* __restrict__ A0, const unsigned short* __restrict__ B0,
    const unsigned short* __restrict__ A1, const unsigned short* __restrict__ B1,
    int M, int K, int Nc,
    float* __restrict__ outF, unsigned short* __restrict__ outH, float alpha) {
    __shared__ __align__(16) unsigned short sA[128 * 32];
    __shared__ __align__(16) unsigned short sB[128 * 32];
    const int tid = threadIdx.x;
    const int lane = tid & 63;
    const int wave = tid >> 6;
    const int bm = blockIdx.x * 128;
    const int bn = blockIdx.y * 128;

    const int r0 = wave * 32 + (lane >> 2);
    const int kcol = (lane & 3) * 8;
    const int ga0 = min(bm + r0, M - 1);
    const int ga1 = min(bm + r0 + 16, M - 1);
    const int gb0 = min(bn + r0, Nc - 1);
    const int gb1 = min(bn + r0 + 16, Nc - 1);
    unsigned short* la0 = &sA[wave * 1024];
    unsigned short* la1 = &sA[wave * 1024 + 512];
    unsigned short* lb0 = &sB[wave * 1024];
    unsigned short* lb1 = &sB[wave * 1024 + 512];

    const int mbase = (wave & 1) * 64 + (lane & 15);
    const int nbase = (wave >> 1) * 64 + (lane & 15);
    const int koff = (lane >> 4) * 8;

    floatx4 acc[4][4], res[4][4];

    #pragma unroll
    for (int pass = 0; pass < 2; pass++) {
        const unsigned short* A = pass ? A1 : A0;
        const unsigned short* B = pass ? B1 : B0;
        const unsigned short* pa0 = A + (size_t)ga0 * K + kcol;
        const unsigned short* pa1 = A + (size_t)ga1 * K + kcol;
        const unsigned short* pb0 = B + (size_t)gb0 * K + kcol;
        const unsigned short* pb1 = B + (size_t)gb1 * K + kcol;
        #pragma unroll
        for (int i = 0; i < 4; i++)
            #pragma unroll
            for (int j = 0; j < 4; j++) acc[i][j] = (floatx4){0.f, 0.f, 0.f, 0.f};

        for (int kk = 0; kk < K; kk += 32) {
            GLL(pa0 + kk, la0);
            GLL(pa1 + kk, la1);
            GLL(pb0 + kk, lb0);
            GLL(pb1 + kk, lb1);
            __syncthreads();
            bf16x8 af[4], bf[4];
            #pragma unroll
            for (int mi = 0; mi < 4; mi++)
                af[mi] = *(const bf16x8*)&sA[(mbase + mi * 16) * 32 + koff];
            #pragma unroll
            for (int ni = 0; ni < 4; ni++)
                bf[ni] = *(const bf16x8*)&sB[(nbase + ni * 16) * 32 + koff];
            #pragma unroll
            for (int mi = 0; mi < 4; mi++)
                #pragma unroll
                for (int ni = 0; ni < 4; ni++)
                    acc[mi][ni] = __builtin_amdgcn_mfma_f32_16x16x32_bf16(
                        af[mi], bf[ni], acc[mi][ni], 0, 0, 0);
            __syncthreads();
        }
        if (pass == 0) {
            #pragma unroll
            for (int mi = 0; mi < 4; mi++)
                #pragma unroll
                for (int ni = 0; ni < 4; ni++)
                    #pragma unroll
                    for (int r = 0; r < 4; r++)
                        res[mi][ni][r] = fmaxf(acc[mi][ni][r], 0.0f);
        }
    }

    const int crow = bm + (wave & 1) * 64 + (lane >> 4) * 4;
    const int ccol = bn + (wave >> 1) * 64 + (lane & 15);
    #pragma unroll
    for (int mi = 0; mi < 4; mi++)
        #pragma unroll
        for (int ni = 0; ni < 4; ni++)
            #pragma unroll
            for (int r = 0; r < 4; r++) {
                int row = crow + mi * 16 + r;
                if (row >= M) continue;
                int col = ccol + ni * 16;
                float v = alpha * (res[mi][ni][r] + fmaxf(acc[mi][ni][r], 0.0f));
                size_t idx = (size_t)row * Nc + col;
                if (outF) outF[idx] = v;
                else      outH[idx] = f2b(v);
            }
}

// ---------------- host orchestration ----------------

extern "C" void kernel_launch(void* const* d_in, const int* in_sizes, int n_in,
                              void* d_out, int out_size, void* d_ws, size_t ws_size,
                              hipStream_t stream) {
    const int F = 256;
    const int N = in_sizes[0] / F;
    const int PEd = in_sizes[1] / N;          // 98
    const int E = in_sizes[2] / 2;            // 800000
    const int KC = F + PEd;                   // 354
    const int KP = (KC + 31) & ~31;           // 384

    const float* x   = (const float*)d_in[0];
    const float* pe  = (const float*)d_in[1];
    const int*   ei0 = (const int*)d_in[2];
    const float* ea0 = (const float*)d_in[3];
    const int*   ei1 = (const int*)d_in[4];
    const float* ea1 = (const float*)d_in[5];
    const float* Wn1 = (const float*)d_in[6];
    const float* Wn2 = (const float*)d_in[7];
    const float* W11 = (const float*)d_in[8];
    const float* W12 = (const float*)d_in[9];
    const float* W21 = (const float*)d_in[10];
    const float* W22 = (const float*)d_in[11];
    const float* W31 = (const float*)d_in[12];
    const float* W32 = (const float*)d_in[13];
    const float* W41 = (const float*)d_in[14];
    const float* W42 = (const float*)d_in[15];
    float* out = (float*)d_out;

    char* p = (char*)d_ws;
    auto alloc = [&](size_t b) -> char* {
        char* r = p;
        p += (b + 255) & ~(size_t)255;
        return r;
    };
    int*   cnt0  = (int*)alloc((size_t)N * 4);
    int*   cnt1  = (int*)alloc((size_t)N * 4);
    int*   off0  = (int*)alloc((size_t)(N + 1) * 4);
    int*   off1  = (int*)alloc((size_t)(N + 1) * 4);
    int*   cur0  = (int*)alloc((size_t)N * 4);
    int*   cur1  = (int*)alloc((size_t)N * 4);
    float* dinv0 = (float*)alloc((size_t)N * 4);
    float* dinv1 = (float*)alloc((size_t)N * 4);
    uint2* rec0  = (uint2*)alloc(((size_t)E + 8ull * N) * 8);   // padded CSR
    uint2* rec1  = (uint2*)alloc(((size_t)E + 8ull * N) * 8);
    unsigned short* wn0c = (unsigned short*)alloc((size_t)F * KP * 2);
    unsigned short* wn1c = (unsigned short*)alloc((size_t)F * KP * 2);
    unsigned short* wc0  = (unsigned short*)alloc((size_t)F * 512 * 2);
    unsigned short* wc1  = (unsigned short*)alloc((size_t)F * 512 * 2);
    unsigned short* wc2  = (unsigned short*)alloc((size_t)F * 512 * 2);
    unsigned short* wc3  = (unsigned short*)alloc((size_t)F * 512 * 2);
    unsigned short* xa   = (unsigned short*)alloc((size_t)N * 512 * 2);  // xa|xb
    unsigned short* xb   = xa + (size_t)N * 256;
    unsigned short* h    = (unsigned short*)alloc((size_t)N * F * 2);
    unsigned short* a12  = (unsigned short*)alloc((size_t)N * 512 * 2);
    unsigned short* xc   = a12;                  // dead after node transforms
    unsigned short* a12bL1 = (unsigned short*)d_out;  // N*512 bf16 == out_size f32
    unsigned short* a12bL2 = xa;                 // xa|xb dead after layer-1 agg

    const int B = 256;
    const int gE = (E + B - 1) / B;
    const int gN = (N + B - 1) / B;
    const int gW = (N + 3) / 4;                  // 4 waves (nodes) per block
    dim3 gemm_grid((N + 127) / 128, 2);
    dim3 gemm_grid2((N + 127) / 128, 2, 2);

    // 1. degree / dinv / padded CSR
    hipMemsetAsync(cnt0, 0, (size_t)N * 4, stream);
    hipMemsetAsync(cnt1, 0, (size_t)N * 4, stream);
    k_cnt2<<<dim3(gE, 2), B, 0, stream>>>(ei0 + E, ei1 + E, E, cnt0, cnt1);
    k_scan2<<<dim3(1, 2), 1024, 0, stream>>>(cnt0, cnt1, off0, off1, N);
    k_prep<<<dim3(gN, 2), B, 0, stream>>>(cnt0, cnt1, off0, off1, dinv0, dinv1, cur0, cur1, N);
    k_fill2<<<dim3(gE, 2), B, 0, stream>>>(ei0, ea0, ei1, ea1, E, dinv0, dinv1,
                                           cur0, cur1, rec0, rec1);
    k_pad<<<dim3(gN, 2), B, 0, stream>>>(cnt0, cnt1, off0, off1, rec0, rec1, N);

    // 2. bf16 conversions
    k_xc<<<((size_t)N * KP + B - 1) / B, B, 0, stream>>>(x, pe, xc, N, F, PEd, KC, KP);
    {
        int tot = 2 * F * KP + 4 * F * 512;
        k_wall<<<(tot + B - 1) / B, B, 0, stream>>>(Wn1, Wn2, W11, W12, W21, W22,
                                                    W31, W32, W41, W42,
                                                    wn0c, wn1c, wc0, wc1, wc2, wc3,
                                                    F, KC, KP);
    }

    // 3. node transforms (both via blockIdx.z) -> xa, xb  [row-major N x 256]
    gemm_bt<<<gemm_grid2, B, 0, stream>>>(xc, wn0c, wn1c, N, KP, F, xa, xb);

    // 4. layer 1: both aggs in one dispatch; then dual GEMM -> h (bf16)
    k_agg<<<dim3(gW, 2), B, 0, stream>>>(xa, xb, off0, off1, rec0, rec1,
                                         dinv0, dinv1, a12, a12bL1, N);
    gemm_dual<<<gemm_grid, B, 0, stream>>>(a12, wc0, a12bL1, wc1, N, 512, F,
                                           nullptr, h, 0.5f);

    // 5. layer 2: both aggs in one dispatch; then dual GEMM -> out (f32)
    k_agg<<<dim3(gW, 2), B, 0, stream>>>(h, h, off0, off1, rec0, rec1,
                                         dinv0, dinv1, a12, a12bL2, N);
    gemm_dual<<<gemm_grid, B, 0, stream>>>(a12, wc2, a12bL2, wc3, N, 512, F,
                                           out, nullptr, 0.5f);
}